// Round 3
// baseline (236.762 us; speedup 1.0000x reference)
//
#include <hip/hip_runtime.h>

// GAT batch: B=32, N=512, Fin=128, Fhid=64, H=8, C=16.  All float I/O is fp32.
#define GB 32
#define GN 512
#define GFIN 128
#define GFH 64
#define GH 8
#define GC 16
#define NEGBIG (-9.0e15f)

typedef short short8 __attribute__((ext_vector_type(8)));   // 8 bf16 (MFMA A/B frag)
typedef float f32x4 __attribute__((ext_vector_type(4)));    // MFMA C/D frag

__device__ __forceinline__ ushort f2bf(float f) {
  unsigned u = __float_as_uint(f);
  return (ushort)((u + 0x7FFFu + ((u >> 16) & 1u)) >> 16);  // RNE
}
__device__ __forceinline__ float bf2f(ushort u) {
  return __uint_as_float(((unsigned)u) << 16);
}
__device__ __forceinline__ unsigned pk2(float a, float b) {
  return (unsigned)f2bf(a) | ((unsigned)f2bf(b) << 16);
}

// ---------------------------------------------------------------------------
// K0: pack adj (int32 0/1) into bitmask words: mw[b*N*16 + n*16 + w], bit i of
// word w = (adj[b][n][32w+i] > 0).
// ---------------------------------------------------------------------------
__global__ __launch_bounds__(256) void k_pack(const int* __restrict__ adj,
                                              unsigned* __restrict__ mw) {
  int idx = blockIdx.x * 256 + threadIdx.x;       // 0 .. B*N*N-1
  int pred = adj[idx] > 0;
  unsigned long long m = __ballot(pred);
  int lane = threadIdx.x & 63;
  if (lane == 0)       mw[idx >> 5] = (unsigned)m;
  else if (lane == 32) mw[idx >> 5] = (unsigned)(m >> 32);
}

// ---------------------------------------------------------------------------
// K1: per (b,h): V = x[b] @ W[h] (512x128 @ 128x64) via MFMA 16x16x32 bf16.
// fp32 inputs converted to bf16 at LDS staging. V stored bf16; f1/f2 exact
// fp32 from accumulators. grid = B*H = 256, block 256 (4 waves).
// ---------------------------------------------------------------------------
__global__ __launch_bounds__(256) void k_gemm1(const float* __restrict__ xg,
                                               const float* __restrict__ Wg,
                                               const float* __restrict__ a1g,
                                               const float* __restrict__ a2g,
                                               ushort* __restrict__ Vg,
                                               float* __restrict__ f1g,
                                               float* __restrict__ f2g) {
  __shared__ ushort Wt[64][136];    // W transposed [j][f] bf16
  __shared__ ushort xl[128][136];   // x row tile [row][f] bf16
  int b = blockIdx.x >> 3, h = blockIdx.x & 7;
  int tid = threadIdx.x, lane = tid & 63, w = tid >> 6;
  int c = lane & 15, q = lane >> 4;

  const float* Wh = Wg + (size_t)h * GFIN * GFH;
  for (int i = tid; i < GFIN * GFH; i += 256) {
    int f = i >> 6, j = i & 63;
    Wt[j][f] = f2bf(Wh[i]);
  }
  __syncthreads();

  // B-frags: whole W[h] in registers. Bf[cb][kk], B[k][n]: k=kk*32+q*8+j, n=cb*16+c
  short8 Bf[4][4];
#pragma unroll
  for (int cb = 0; cb < 4; ++cb)
#pragma unroll
    for (int kk = 0; kk < 4; ++kk)
      Bf[cb][kk] = *(const short8*)&Wt[cb * 16 + c][kk * 32 + q * 8];

  float a1v[4], a2v[4];
#pragma unroll
  for (int cb = 0; cb < 4; ++cb) {
    a1v[cb] = a1g[h * 64 + cb * 16 + c];
    a2v[cb] = a2g[h * 64 + cb * 16 + c];
  }

  const float* xb = xg + (size_t)b * GN * GFIN;
  size_t bh = blockIdx.x;
  ushort* Vo = Vg + bh * GN * GFH;
  float* f1o = f1g + bh * GN;
  float* f2o = f2g + bh * GN;

  for (int r0 = 0; r0 < GN; r0 += 128) {
    __syncthreads();
    for (int u = tid; u < 128 * 32; u += 256) {   // 32 float4 per row
      int row = u >> 5, c4 = u & 31;
      float4 xf = *(const float4*)&xb[(size_t)(r0 + row) * GFIN + c4 * 4];
      ushort4 us;
      us.x = f2bf(xf.x); us.y = f2bf(xf.y); us.z = f2bf(xf.z); us.w = f2bf(xf.w);
      *(ushort4*)&xl[row][c4 * 4] = us;
    }
    __syncthreads();

    f32x4 acc[2][4];
#pragma unroll
    for (int r = 0; r < 2; ++r)
#pragma unroll
      for (int cb = 0; cb < 4; ++cb) acc[r][cb] = (f32x4){0.f, 0.f, 0.f, 0.f};

#pragma unroll
    for (int kk = 0; kk < 4; ++kk) {
      short8 A0 = *(const short8*)&xl[(w * 2 + 0) * 16 + c][kk * 32 + q * 8];
      short8 A1 = *(const short8*)&xl[(w * 2 + 1) * 16 + c][kk * 32 + q * 8];
#pragma unroll
      for (int cb = 0; cb < 4; ++cb) {
        acc[0][cb] = __builtin_amdgcn_mfma_f32_16x16x32_bf16(A0, Bf[cb][kk], acc[0][cb], 0, 0, 0);
        acc[1][cb] = __builtin_amdgcn_mfma_f32_16x16x32_bf16(A1, Bf[cb][kk], acc[1][cb], 0, 0, 0);
      }
    }

    // Epilogue: C/D layout col=lane&15, row=(lane>>4)*4+reg.
#pragma unroll
    for (int rbi = 0; rbi < 2; ++rbi) {
#pragma unroll
      for (int i = 0; i < 4; ++i) {
        int row = r0 + (w * 2 + rbi) * 16 + q * 4 + i;
        float v1 = 0.f, v2 = 0.f;
#pragma unroll
        for (int cb = 0; cb < 4; ++cb) {
          float val = acc[rbi][cb][i];
          Vo[(size_t)row * GFH + cb * 16 + c] = f2bf(val);
          v1 += val * a1v[cb];
          v2 += val * a2v[cb];
        }
#pragma unroll
        for (int off = 1; off < 16; off <<= 1) {   // reduce over 16 cols (c)
          v1 += __shfl_xor(v1, off);
          v2 += __shfl_xor(v2, off);
        }
        if (c == 0) { f1o[row] = v1; f2o[row] = v2; }
      }
    }
  }
}

// ---------------------------------------------------------------------------
// K2: layer-1 attention. grid = B*H*2 (256 rows/block), block 256 (4 waves).
// fp32 masked softmax -> P bf16 (LDS) -> MFMA P@V (V bf16, B-frags in regs)
// -> elu -> xcat fp32 at [b][n][h*64+j].
// ---------------------------------------------------------------------------
__global__ __launch_bounds__(256) void k_attn1(const ushort* __restrict__ Vglob,
                                               const unsigned* __restrict__ mwg,
                                               const float* __restrict__ f1g,
                                               const float* __restrict__ f2g,
                                               float* __restrict__ xcat) {
  constexpr int RPB = 256, RT = 32;
  __shared__ ushort P[RT][520];          // bf16, stride 520 (16B-aligned rows)
  __shared__ float f2s[GN];
  __shared__ float f1s[RPB];

  int tid = threadIdx.x, lane = tid & 63, w = tid >> 6;
  int c = lane & 15, q = lane >> 4;

  int bh = blockIdx.x >> 1, half = blockIdx.x & 1;
  int b = bh >> 3, h = bh & 7, r0 = half * RPB;
  const ushort* V = Vglob + (size_t)bh * GN * GFH;
  const float* f1w = f1g + (size_t)bh * GN;
  const float* f2w = f2g + (size_t)bh * GN;
  const unsigned* mwb = mwg + (size_t)b * GN * 16;

  for (int i = tid; i < GN; i += 256) f2s[i] = f2w[i];
  for (int i = tid; i < RPB; i += 256) f1s[i] = f1w[r0 + i];

  // Wave w owns V columns w*16..w*16+15: B[k][n]: k=kk*32+q*8+j, n=w*16+c.
  short8 Bf[16];
#pragma unroll
  for (int kk = 0; kk < 16; ++kk) {
    short8 bb;
#pragma unroll
    for (int i = 0; i < 8; ++i) {
      int k = kk * 32 + q * 8 + i;
      bb[i] = (short)V[(size_t)k * GFH + w * 16 + c];
    }
    Bf[kk] = bb;
  }
  __syncthreads();

  float f2v[8];
#pragma unroll
  for (int i = 0; i < 8; ++i) f2v[i] = f2s[lane * 8 + i];

  for (int t0 = 0; t0 < RPB; t0 += RT) {
    // ---- scores: wave w rows t0+w+4*ri, lane covers cols lane*8..lane*8+7
#pragma unroll
    for (int ri = 0; ri < RT / 4; ++ri) {
      int rl = t0 + w + 4 * ri;
      int r = r0 + rl;
      float f1r = f1s[rl];
      unsigned mword = mwb[(size_t)r * 16 + (lane >> 2)];
      unsigned mb = (mword >> (8 * (lane & 3))) & 0xffu;
      float s[8];
#pragma unroll
      for (int i = 0; i < 8; ++i) {
        float t = f1r + f2v[i];
        t = fmaxf(t, 0.2f * t);          // LeakyReLU(0.2)
        s[i] = ((mb >> i) & 1u) ? t : NEGBIG;
      }
      float M = s[0];
#pragma unroll
      for (int i = 1; i < 8; ++i) M = fmaxf(M, s[i]);
#pragma unroll
      for (int off = 1; off < 64; off <<= 1) M = fmaxf(M, __shfl_xor(M, off));
      float p[8], L = 0.f;
#pragma unroll
      for (int i = 0; i < 8; ++i) { p[i] = __expf(s[i] - M); L += p[i]; }
#pragma unroll
      for (int off = 1; off < 64; off <<= 1) L += __shfl_xor(L, off);
      float inv = 1.f / fmaxf(L, 1e-30f);
      uint4 u;
      u.x = pk2(p[0] * inv, p[1] * inv);
      u.y = pk2(p[2] * inv, p[3] * inv);
      u.z = pk2(p[4] * inv, p[5] * inv);
      u.w = pk2(p[6] * inv, p[7] * inv);
      *(uint4*)&P[w + 4 * ri][lane * 8] = u;
    }
    __syncthreads();

    // ---- MFMA: D(32 x 64) = P(32 x 512) @ V(512 x 64), wave w = cols w*16+..
    f32x4 acc0 = (f32x4){0.f, 0.f, 0.f, 0.f};
    f32x4 acc1 = (f32x4){0.f, 0.f, 0.f, 0.f};
#pragma unroll
    for (int kk = 0; kk < 16; ++kk) {
      short8 A0 = *(const short8*)&P[c][kk * 32 + q * 8];
      short8 A1 = *(const short8*)&P[16 + c][kk * 32 + q * 8];
      acc0 = __builtin_amdgcn_mfma_f32_16x16x32_bf16(A0, Bf[kk], acc0, 0, 0, 0);
      acc1 = __builtin_amdgcn_mfma_f32_16x16x32_bf16(A1, Bf[kk], acc1, 0, 0, 0);
    }
#pragma unroll
    for (int rbi = 0; rbi < 2; ++rbi) {
      f32x4 a = rbi ? acc1 : acc0;
#pragma unroll
      for (int i = 0; i < 4; ++i) {
        int row = r0 + t0 + rbi * 16 + q * 4 + i;
        float v = a[i];
        v = v > 0.f ? v : expm1f(v);     // elu
        xcat[((size_t)(b * GN + row)) * (GH * GFH) + h * 64 + w * 16 + c] = v;
      }
    }
    __syncthreads();
  }
}

// ---------------------------------------------------------------------------
// K3: h_out = x_cat[b] @ W_out (512x512 @ 512x16), pure fp32 VALU + exact
// f1b/f2b. grid = B*8 (64 rows/block), block 256: rg=tid>>4 (4 rows), cg=col.
// ---------------------------------------------------------------------------
__global__ __launch_bounds__(256) void k_gemm2(const float* __restrict__ xc,
                                               const float* __restrict__ Wog,
                                               const float* __restrict__ a1g,
                                               const float* __restrict__ a2g,
                                               float* __restrict__ hg,
                                               float* __restrict__ f1g,
                                               float* __restrict__ f2g) {
  __shared__ float Wt[16][132];    // W chunk transposed [c][k]
  __shared__ float xl[64][132];    // x chunk [r][k]
  int b = blockIdx.x >> 3, r0 = (blockIdx.x & 7) * 64;
  int tid = threadIdx.x, rg = tid >> 4, cg = tid & 15;

  const float* xb = xc + ((size_t)b * GN + r0) * 512;
  float acc[4] = {0.f, 0.f, 0.f, 0.f};

  for (int kc = 0; kc < 4; ++kc) {
    __syncthreads();
    for (int i = tid; i < 128 * 16; i += 256) {        // W chunk 128x16
      int k = i >> 4, cc = i & 15;
      Wt[cc][k] = Wog[(size_t)(kc * 128 + k) * 16 + cc];
    }
    for (int u = tid; u < 64 * 32; u += 256) {         // x chunk 64x128
      int r = u >> 5, c4 = u & 31;
      *(float4*)&xl[r][c4 * 4] =
          *(const float4*)&xb[(size_t)r * 512 + kc * 128 + c4 * 4];
    }
    __syncthreads();
    for (int k = 0; k < 128; k += 4) {
      float4 w4 = *(const float4*)&Wt[cg][k];
#pragma unroll
      for (int rr = 0; rr < 4; ++rr) {
        float4 x4 = *(const float4*)&xl[rg * 4 + rr][k];
        acc[rr] = fmaf(x4.x, w4.x, acc[rr]);
        acc[rr] = fmaf(x4.y, w4.y, acc[rr]);
        acc[rr] = fmaf(x4.z, w4.z, acc[rr]);
        acc[rr] = fmaf(x4.w, w4.w, acc[rr]);
      }
    }
  }

  float a1v = a1g[cg], a2v = a2g[cg];
#pragma unroll
  for (int rr = 0; rr < 4; ++rr) {
    int row = r0 + rg * 4 + rr;
    hg[((size_t)b * GN + row) * GC + cg] = acc[rr];
    float v1 = acc[rr] * a1v, v2 = acc[rr] * a2v;
#pragma unroll
    for (int off = 1; off < 16; off <<= 1) {
      v1 += __shfl_xor(v1, off);
      v2 += __shfl_xor(v2, off);
    }
    if (cg == 0) {
      f1g[(size_t)b * GN + row] = v1;
      f2g[(size_t)b * GN + row] = v2;
    }
  }
}

// ---------------------------------------------------------------------------
// K4: layer-2 attention (concat=False): out = softmax(mask(LR(f1+f2))) @ h.
// Pure fp32. grid = B*64 (8 rows/block), block 256.
// ---------------------------------------------------------------------------
__global__ __launch_bounds__(256) void k_attn2(const float* __restrict__ hg,
                                               const unsigned* __restrict__ mwg,
                                               const float* __restrict__ f1g,
                                               const float* __restrict__ f2g,
                                               float* __restrict__ outg) {
  __shared__ float P[8][516];      // fp32 att rows
  __shared__ float ht[16][524];    // h transposed [c][j]
  int b = blockIdx.x >> 6, r0 = (blockIdx.x & 63) * 8;
  int tid = threadIdx.x, lane = tid & 63, w = tid >> 6;

  const float* V = hg + (size_t)b * GN * GC;
  for (int i = tid; i < GN * GC; i += 256) ht[i & 15][i >> 4] = V[i];

  const float* f2w = f2g + (size_t)b * GN;
  float f2v[8];
#pragma unroll
  for (int i = 0; i < 8; ++i) f2v[i] = f2w[lane * 8 + i];
  const unsigned* mwb = mwg + (size_t)b * GN * 16;

#pragma unroll
  for (int rr = 0; rr < 2; ++rr) {           // wave w -> rows w*2, w*2+1
    int rl = w * 2 + rr;
    int r = r0 + rl;
    float f1r = f1g[(size_t)b * GN + r];
    unsigned mword = mwb[(size_t)r * 16 + (lane >> 2)];
    unsigned mb = (mword >> (8 * (lane & 3))) & 0xffu;
    float s[8];
#pragma unroll
    for (int i = 0; i < 8; ++i) {
      float t = f1r + f2v[i];
      t = fmaxf(t, 0.2f * t);
      s[i] = ((mb >> i) & 1u) ? t : NEGBIG;
    }
    float M = s[0];
#pragma unroll
    for (int i = 1; i < 8; ++i) M = fmaxf(M, s[i]);
#pragma unroll
    for (int off = 1; off < 64; off <<= 1) M = fmaxf(M, __shfl_xor(M, off));
    float p[8], L = 0.f;
#pragma unroll
    for (int i = 0; i < 8; ++i) { p[i] = __expf(s[i] - M); L += p[i]; }
#pragma unroll
    for (int off = 1; off < 64; off <<= 1) L += __shfl_xor(L, off);
    float inv = 1.f / fmaxf(L, 1e-30f);
    float4 u0 = {p[0] * inv, p[1] * inv, p[2] * inv, p[3] * inv};
    float4 u1 = {p[4] * inv, p[5] * inv, p[6] * inv, p[7] * inv};
    *(float4*)&P[rl][lane * 8] = u0;
    *(float4*)&P[rl][lane * 8 + 4] = u1;
  }
  __syncthreads();

  // PV: thread -> (row=tid>>5, col=(tid>>1)&15, half=tid&1)
  int row = tid >> 5, col = (tid >> 1) & 15, hf = tid & 1;
  float acc = 0.f;
  for (int j = hf * 256; j < hf * 256 + 256; j += 4) {
    float4 p4 = *(const float4*)&P[row][j];
    float4 h4 = *(const float4*)&ht[col][j];
    acc = fmaf(p4.x, h4.x, acc);
    acc = fmaf(p4.y, h4.y, acc);
    acc = fmaf(p4.z, h4.z, acc);
    acc = fmaf(p4.w, h4.w, acc);
  }
  acc += __shfl_xor(acc, 1);
  if (hf == 0)
    outg[((size_t)(b * GN) + r0 + row) * GC + col] = acc;
}

// ---------------------------------------------------------------------------
extern "C" void kernel_launch(void* const* d_in, const int* in_sizes, int n_in,
                              void* d_out, int out_size, void* d_ws, size_t ws_size,
                              hipStream_t stream) {
  (void)in_sizes; (void)n_in; (void)out_size;
  const float* x   = (const float*)d_in[0];   // [32,512,128] fp32
  const int*   adj = (const int*)d_in[1];     // [32,512,512] i32
  const float* Whd = (const float*)d_in[2];   // [8,128,64] fp32
  const float* a1h = (const float*)d_in[3];   // [8,64]
  const float* a2h = (const float*)d_in[4];   // [8,64]
  const float* Wo  = (const float*)d_in[5];   // [512,16]
  const float* a1o = (const float*)d_in[6];   // [16]
  const float* a2o = (const float*)d_in[7];   // [16]

  size_t off = 0;
  char* base = (char*)d_ws;
  unsigned* mw = (unsigned*)(base + off); off += (size_t)GB * GN * 16 * 4;       // 1 MB
  ushort* V    = (ushort*)(base + off);   off += (size_t)GB * GH * GN * GFH * 2; // 16.8 MB
  float* xcat  = (float*)(base + off);    off += (size_t)GB * GN * GH * GFH * 4; // 33.6 MB
  float* hout  = (float*)(base + off);    off += (size_t)GB * GN * GC * 4;       // 0.5 MB
  float* f1    = (float*)(base + off);    off += (size_t)GB * GH * GN * 4;       // 0.5 MB
  float* f2    = (float*)(base + off);    off += (size_t)GB * GH * GN * 4;       // 0.5 MB
  float* f1b   = (float*)(base + off);    off += (size_t)GB * GN * 4;
  float* f2b   = (float*)(base + off);    off += (size_t)GB * GN * 4;            // ~53 MB

  if (ws_size < off) return;   // diagnostic: zeros (absmax 0.414) = ws too small

  hipLaunchKernelGGL(k_pack, dim3((GB * GN * GN) / 256), dim3(256), 0, stream, adj, mw);
  hipLaunchKernelGGL(k_gemm1, dim3(GB * GH), dim3(256), 0, stream,
                     x, Whd, a1h, a2h, V, f1, f2);
  hipLaunchKernelGGL(k_attn1, dim3(GB * GH * 2), dim3(256), 0, stream,
                     V, mw, f1, f2, xcat);
  hipLaunchKernelGGL(k_gemm2, dim3(GB * 8), dim3(256), 0, stream,
                     xcat, Wo, a1o, a2o, hout, f1b, f2b);
  hipLaunchKernelGGL(k_attn2, dim3(GB * 64), dim3(256), 0, stream,
                     hout, mw, f1b, f2b, (float*)d_out);
}

// Round 4
// 213.887 us; speedup vs baseline: 1.1070x; 1.1070x over previous
//
#include <hip/hip_runtime.h>
#include <hip/hip_bf16.h>

// GAT batch: B=32, N=512, Fin=128, Fhid=64, H=8, C=16.  All float I/O is fp32.
#define GB 32
#define GN 512
#define GFIN 128
#define GFH 64
#define GH 8
#define GC 16
#define NEGBIG (-9.0e15f)

typedef short short8 __attribute__((ext_vector_type(8)));   // 8 bf16 (MFMA A/B frag)
typedef float f32x4 __attribute__((ext_vector_type(4)));    // MFMA C/D frag

__device__ __forceinline__ ushort f2bf(float f) {
  unsigned u = __float_as_uint(f);
  return (ushort)((u + 0x7FFFu + ((u >> 16) & 1u)) >> 16);  // RNE
}
__device__ __forceinline__ unsigned pk2(float a, float b) {
  // packed f32->bf16 RNE pair (v_cvt_pk_bf16_f32 on gfx950)
  float2 f2; f2.x = a; f2.y = b;
  __hip_bfloat162 h = __float22bfloat162_rn(f2);
  union { __hip_bfloat162 h; unsigned u; } cv;
  cv.h = h;
  return cv.u;
}

// ---------------------------------------------------------------------------
// K01: fused adj-pack + gemm1.
// Blocks [0,1024): per (bh, rquad): V^T = (x[b] @ W[h])^T  (stored [bh][col][k]
// bf16) + exact fp32 f1/f2.  Blocks [1024,5120): pack adj bits into mw.
// ---------------------------------------------------------------------------
__global__ __launch_bounds__(256) void k_pack_gemm1(
    const int* __restrict__ adj, unsigned* __restrict__ mw,
    const float* __restrict__ xg, const float* __restrict__ Wg,
    const float* __restrict__ a1g, const float* __restrict__ a2g,
    ushort* __restrict__ VTg, float* __restrict__ f1g, float* __restrict__ f2g) {
  __shared__ ushort Wt[64][136];    // W transposed [j][f] bf16
  __shared__ ushort xl[128][136];   // x row tile [row][f] bf16
  int blk = blockIdx.x;
  int tid = threadIdx.x;

  if (blk >= 1024) {                // ---- pack path ----
    int pblk = blk - 1024;          // 4096 blocks x 8 chunks x 256 = B*N*N
    int lane = tid & 63;
#pragma unroll
    for (int it = 0; it < 8; ++it) {
      int idx = (pblk * 8 + it) * 256 + tid;
      int pred = adj[idx] > 0;
      unsigned long long m = __ballot(pred);
      if (lane == 0)       mw[idx >> 5] = (unsigned)m;
      else if (lane == 32) mw[idx >> 5] = (unsigned)(m >> 32);
    }
    return;
  }

  // ---- gemm1 path: blk = bh*4 + rquad ----
  int bh = blk >> 2, rq = blk & 3;
  int b = bh >> 3, h = bh & 7;
  int r0 = rq * 128;
  int lane = tid & 63, w = tid >> 6;
  int c = lane & 15, q = lane >> 4;

  const float* Wh = Wg + (size_t)h * GFIN * GFH;
  for (int i = tid; i < GFIN * GFH; i += 256) {
    int f = i >> 6, j = i & 63;
    Wt[j][f] = f2bf(Wh[i]);
  }
  const float* xb = xg + ((size_t)b * GN + r0) * GFIN;
  for (int u = tid; u < 128 * 32; u += 256) {   // 32 float4 per row
    int row = u >> 5, c4 = u & 31;
    float4 xf = *(const float4*)&xb[(size_t)row * GFIN + c4 * 4];
    uint2 us;
    us.x = pk2(xf.x, xf.y);
    us.y = pk2(xf.z, xf.w);
    *(uint2*)&xl[row][c4 * 4] = us;
  }
  __syncthreads();

  // B-frags: whole W[h]. Bf[cb][kk]: B[k=kk*32+q*8+j][n=cb*16+c]
  short8 Bf[4][4];
#pragma unroll
  for (int cb = 0; cb < 4; ++cb)
#pragma unroll
    for (int kk = 0; kk < 4; ++kk)
      Bf[cb][kk] = *(const short8*)&Wt[cb * 16 + c][kk * 32 + q * 8];

  float a1v[4], a2v[4];
#pragma unroll
  for (int cb = 0; cb < 4; ++cb) {
    a1v[cb] = a1g[h * 64 + cb * 16 + c];
    a2v[cb] = a2g[h * 64 + cb * 16 + c];
  }

  f32x4 acc[2][4];
#pragma unroll
  for (int r = 0; r < 2; ++r)
#pragma unroll
    for (int cb = 0; cb < 4; ++cb) acc[r][cb] = (f32x4){0.f, 0.f, 0.f, 0.f};

#pragma unroll
  for (int kk = 0; kk < 4; ++kk) {
    short8 A0 = *(const short8*)&xl[(w * 2 + 0) * 16 + c][kk * 32 + q * 8];
    short8 A1 = *(const short8*)&xl[(w * 2 + 1) * 16 + c][kk * 32 + q * 8];
#pragma unroll
    for (int cb = 0; cb < 4; ++cb) {
      acc[0][cb] = __builtin_amdgcn_mfma_f32_16x16x32_bf16(A0, Bf[cb][kk], acc[0][cb], 0, 0, 0);
      acc[1][cb] = __builtin_amdgcn_mfma_f32_16x16x32_bf16(A1, Bf[cb][kk], acc[1][cb], 0, 0, 0);
    }
  }

  // Epilogue: V^T store ([bh][col][k], ushort4 over i) + exact fp32 f1/f2.
  ushort* VT = VTg + (size_t)bh * GN * GFH;
  float* f1o = f1g + (size_t)bh * GN;
  float* f2o = f2g + (size_t)bh * GN;
#pragma unroll
  for (int rbi = 0; rbi < 2; ++rbi) {
    int rowb = r0 + (w * 2 + rbi) * 16 + q * 4;   // 4 consecutive rows
    float v1[4] = {0.f, 0.f, 0.f, 0.f}, v2[4] = {0.f, 0.f, 0.f, 0.f};
#pragma unroll
    for (int cb = 0; cb < 4; ++cb) {
      f32x4 a = acc[rbi][cb];
      uint2 vs;
      vs.x = pk2(a[0], a[1]);
      vs.y = pk2(a[2], a[3]);
      *(uint2*)&VT[(size_t)(cb * 16 + c) * GN + rowb] = vs;
#pragma unroll
      for (int i = 0; i < 4; ++i) {
        v1[i] += a[i] * a1v[cb];
        v2[i] += a[i] * a2v[cb];
      }
    }
#pragma unroll
    for (int i = 0; i < 4; ++i) {
#pragma unroll
      for (int off = 1; off < 16; off <<= 1) {   // reduce over 16 cols (c)
        v1[i] += __shfl_xor(v1[i], off);
        v2[i] += __shfl_xor(v2[i], off);
      }
      if (c == 0) { f1o[rowb + i] = v1[i]; f2o[rowb + i] = v2[i]; }
    }
  }
}

// ---------------------------------------------------------------------------
// K2: layer-1 attention v2. grid = B*H*4 (128 rows/block), block 256 (4 waves).
// Max-free fp32 softmax (scores bounded), one shuffle-sum for L (shared via
// LDS), unnormalized P bf16 -> MFMA P@V (B-frags coalesced from V^T) ->
// normalize+elu in epilogue -> xcat fp32.
// ---------------------------------------------------------------------------
__global__ __launch_bounds__(256, 4) void k_attn1(
    const ushort* __restrict__ VTg, const unsigned* __restrict__ mwg,
    const float* __restrict__ f1g, const float* __restrict__ f2g,
    float* __restrict__ xcat) {
  __shared__ ushort P[32][520];          // bf16 unnormalized att tile
  __shared__ float Ls[32];               // per-row sums
  int blk = blockIdx.x;                  // 1024 = bh*4 + rquad
  int bh = blk >> 2, rq = blk & 3;
  int b = bh >> 3, h = bh & 7;
  int r0 = rq * 128;
  int tid = threadIdx.x, lane = tid & 63, w = tid >> 6;
  int c = lane & 15, q = lane >> 4;

  const unsigned* mwb = mwg + (size_t)b * GN * 16;
  const float* f1w = f1g + (size_t)bh * GN;
  const float* f2w = f2g + (size_t)bh * GN;

  // f2 for this lane's 8 columns, straight from global (coalesced float4).
  float4 fa = *(const float4*)&f2w[lane * 8];
  float4 fb = *(const float4*)&f2w[lane * 8 + 4];
  float f2v[8] = {fa.x, fa.y, fa.z, fa.w, fb.x, fb.y, fb.z, fb.w};

  // B-frags from V^T: lane (c,q) col w*16+c, k = kk*32+q*8.. (+7): contiguous.
  const ushort* VT = VTg + (size_t)bh * GN * GFH + (size_t)(w * 16 + c) * GN + q * 8;
  short8 Bf[16];
#pragma unroll
  for (int kk = 0; kk < 16; ++kk) Bf[kk] = *(const short8*)&VT[kk * 32];

  for (int t = 0; t < 4; ++t) {
    int tb = r0 + t * 32;
    // ---- scores: wave w rows tb + w + 4*ri ----
    float f1r[8];
    unsigned mword[8];
#pragma unroll
    for (int ri = 0; ri < 8; ++ri) {
      int r = tb + w + 4 * ri;
      f1r[ri] = f1w[r];
      mword[ri] = mwb[(size_t)r * 16 + (lane >> 2)];
    }
#pragma unroll
    for (int ri = 0; ri < 8; ++ri) {
      int rl = w + 4 * ri;
      unsigned mb = (mword[ri] >> (8 * (lane & 3))) & 0xffu;
      float p[8], L = 0.f;
#pragma unroll
      for (int i = 0; i < 8; ++i) {
        float tt = f1r[ri] + f2v[i];
        tt = fmaxf(tt, 0.2f * tt);       // LeakyReLU(0.2); |tt| <~ 10 -> exp safe
        float e = __expf(tt);
        p[i] = ((mb >> i) & 1u) ? e : 0.f;
        L += p[i];
      }
#pragma unroll
      for (int off = 1; off < 64; off <<= 1) L += __shfl_xor(L, off);
      uint4 u;
      u.x = pk2(p[0], p[1]);
      u.y = pk2(p[2], p[3]);
      u.z = pk2(p[4], p[5]);
      u.w = pk2(p[6], p[7]);
      *(uint4*)&P[rl][lane * 8] = u;
      if (lane == 0) Ls[rl] = L;
    }
    __syncthreads();

    // ---- MFMA: D(32 x 64) = P(32 x 512) @ V(512 x 64), wave w = 16 cols ----
    f32x4 acc0 = (f32x4){0.f, 0.f, 0.f, 0.f};
    f32x4 acc1 = (f32x4){0.f, 0.f, 0.f, 0.f};
#pragma unroll
    for (int kk = 0; kk < 16; ++kk) {
      short8 A0 = *(const short8*)&P[c][kk * 32 + q * 8];
      short8 A1 = *(const short8*)&P[16 + c][kk * 32 + q * 8];
      acc0 = __builtin_amdgcn_mfma_f32_16x16x32_bf16(A0, Bf[kk], acc0, 0, 0, 0);
      acc1 = __builtin_amdgcn_mfma_f32_16x16x32_bf16(A1, Bf[kk], acc1, 0, 0, 0);
    }
#pragma unroll
    for (int rbi = 0; rbi < 2; ++rbi) {
      f32x4 a = rbi ? acc1 : acc0;
#pragma unroll
      for (int i = 0; i < 4; ++i) {
        int rt = rbi * 16 + q * 4 + i;
        float inv = 1.f / fmaxf(Ls[rt], 1e-30f);
        float v = a[i] * inv;
        v = v > 0.f ? v : expm1f(v);     // elu
        int row = tb + rt;
        xcat[((size_t)(b * GN + row)) * (GH * GFH) + h * 64 + w * 16 + c] = v;
      }
    }
    __syncthreads();
  }
}

// ---------------------------------------------------------------------------
// K3: h_out = x_cat[b] @ W_out (512x512 @ 512x16), pure fp32 VALU + exact
// f1b/f2b. grid = B*8 (64 rows/block), block 256. (unchanged from R3)
// ---------------------------------------------------------------------------
__global__ __launch_bounds__(256) void k_gemm2(const float* __restrict__ xc,
                                               const float* __restrict__ Wog,
                                               const float* __restrict__ a1g,
                                               const float* __restrict__ a2g,
                                               float* __restrict__ hg,
                                               float* __restrict__ f1g,
                                               float* __restrict__ f2g) {
  __shared__ float Wt[16][132];    // W chunk transposed [c][k]
  __shared__ float xl[64][132];    // x chunk [r][k]
  int b = blockIdx.x >> 3, r0 = (blockIdx.x & 7) * 64;
  int tid = threadIdx.x, rg = tid >> 4, cg = tid & 15;

  const float* xb = xc + ((size_t)b * GN + r0) * 512;
  float acc[4] = {0.f, 0.f, 0.f, 0.f};

  for (int kc = 0; kc < 4; ++kc) {
    __syncthreads();
    for (int i = tid; i < 128 * 16; i += 256) {        // W chunk 128x16
      int k = i >> 4, cc = i & 15;
      Wt[cc][k] = Wog[(size_t)(kc * 128 + k) * 16 + cc];
    }
    for (int u = tid; u < 64 * 32; u += 256) {         // x chunk 64x128
      int r = u >> 5, c4 = u & 31;
      *(float4*)&xl[r][c4 * 4] =
          *(const float4*)&xb[(size_t)r * 512 + kc * 128 + c4 * 4];
    }
    __syncthreads();
    for (int k = 0; k < 128; k += 4) {
      float4 w4 = *(const float4*)&Wt[cg][k];
#pragma unroll
      for (int rr = 0; rr < 4; ++rr) {
        float4 x4 = *(const float4*)&xl[rg * 4 + rr][k];
        acc[rr] = fmaf(x4.x, w4.x, acc[rr]);
        acc[rr] = fmaf(x4.y, w4.y, acc[rr]);
        acc[rr] = fmaf(x4.z, w4.z, acc[rr]);
        acc[rr] = fmaf(x4.w, w4.w, acc[rr]);
      }
    }
  }

  float a1v = a1g[cg], a2v = a2g[cg];
#pragma unroll
  for (int rr = 0; rr < 4; ++rr) {
    int row = r0 + rg * 4 + rr;
    hg[((size_t)b * GN + row) * GC + cg] = acc[rr];
    float v1 = acc[rr] * a1v, v2 = acc[rr] * a2v;
#pragma unroll
    for (int off = 1; off < 16; off <<= 1) {
      v1 += __shfl_xor(v1, off);
      v2 += __shfl_xor(v2, off);
    }
    if (cg == 0) {
      f1g[(size_t)b * GN + row] = v1;
      f2g[(size_t)b * GN + row] = v2;
    }
  }
}

// ---------------------------------------------------------------------------
// K4: layer-2 attention (concat=False). Pure fp32. grid = B*64 (8 rows/block).
// (unchanged from R3)
// ---------------------------------------------------------------------------
__global__ __launch_bounds__(256) void k_attn2(const float* __restrict__ hg,
                                               const unsigned* __restrict__ mwg,
                                               const float* __restrict__ f1g,
                                               const float* __restrict__ f2g,
                                               float* __restrict__ outg) {
  __shared__ float P[8][516];      // fp32 att rows
  __shared__ float ht[16][524];    // h transposed [c][j]
  int b = blockIdx.x >> 6, r0 = (blockIdx.x & 63) * 8;
  int tid = threadIdx.x, lane = tid & 63, w = tid >> 6;

  const float* V = hg + (size_t)b * GN * GC;
  for (int i = tid; i < GN * GC; i += 256) ht[i & 15][i >> 4] = V[i];

  const float* f2w = f2g + (size_t)b * GN;
  float f2v[8];
#pragma unroll
  for (int i = 0; i < 8; ++i) f2v[i] = f2w[lane * 8 + i];
  const unsigned* mwb = mwg + (size_t)b * GN * 16;

#pragma unroll
  for (int rr = 0; rr < 2; ++rr) {           // wave w -> rows w*2, w*2+1
    int rl = w * 2 + rr;
    int r = r0 + rl;
    float f1r = f1g[(size_t)b * GN + r];
    unsigned mword = mwb[(size_t)r * 16 + (lane >> 2)];
    unsigned mb = (mword >> (8 * (lane & 3))) & 0xffu;
    float s[8];
#pragma unroll
    for (int i = 0; i < 8; ++i) {
      float t = f1r + f2v[i];
      t = fmaxf(t, 0.2f * t);
      s[i] = ((mb >> i) & 1u) ? t : NEGBIG;
    }
    float M = s[0];
#pragma unroll
    for (int i = 1; i < 8; ++i) M = fmaxf(M, s[i]);
#pragma unroll
    for (int off = 1; off < 64; off <<= 1) M = fmaxf(M, __shfl_xor(M, off));
    float p[8], L = 0.f;
#pragma unroll
    for (int i = 0; i < 8; ++i) { p[i] = __expf(s[i] - M); L += p[i]; }
#pragma unroll
    for (int off = 1; off < 64; off <<= 1) L += __shfl_xor(L, off);
    float inv = 1.f / fmaxf(L, 1e-30f);
    float4 u0 = {p[0] * inv, p[1] * inv, p[2] * inv, p[3] * inv};
    float4 u1 = {p[4] * inv, p[5] * inv, p[6] * inv, p[7] * inv};
    *(float4*)&P[rl][lane * 8] = u0;
    *(float4*)&P[rl][lane * 8 + 4] = u1;
  }
  __syncthreads();

  // PV: thread -> (row=tid>>5, col=(tid>>1)&15, half=tid&1)
  int row = tid >> 5, col = (tid >> 1) & 15, hf = tid & 1;
  float acc = 0.f;
  for (int j = hf * 256; j < hf * 256 + 256; j += 4) {
    float4 p4 = *(const float4*)&P[row][j];
    float4 h4 = *(const float4*)&ht[col][j];
    acc = fmaf(p4.x, h4.x, acc);
    acc = fmaf(p4.y, h4.y, acc);
    acc = fmaf(p4.z, h4.z, acc);
    acc = fmaf(p4.w, h4.w, acc);
  }
  acc += __shfl_xor(acc, 1);
  if (hf == 0)
    outg[((size_t)(b * GN) + r0 + row) * GC + col] = acc;
}

// ---------------------------------------------------------------------------
extern "C" void kernel_launch(void* const* d_in, const int* in_sizes, int n_in,
                              void* d_out, int out_size, void* d_ws, size_t ws_size,
                              hipStream_t stream) {
  (void)in_sizes; (void)n_in; (void)out_size;
  const float* x   = (const float*)d_in[0];   // [32,512,128] fp32
  const int*   adj = (const int*)d_in[1];     // [32,512,512] i32
  const float* Whd = (const float*)d_in[2];   // [8,128,64] fp32
  const float* a1h = (const float*)d_in[3];   // [8,64]
  const float* a2h = (const float*)d_in[4];   // [8,64]
  const float* Wo  = (const float*)d_in[5];   // [512,16]
  const float* a1o = (const float*)d_in[6];   // [16]
  const float* a2o = (const float*)d_in[7];   // [16]

  size_t off = 0;
  char* base = (char*)d_ws;
  unsigned* mw = (unsigned*)(base + off); off += (size_t)GB * GN * 16 * 4;       // 1 MB
  ushort* VT   = (ushort*)(base + off);   off += (size_t)GB * GH * GN * GFH * 2; // 16.8 MB
  float* xcat  = (float*)(base + off);    off += (size_t)GB * GN * GH * GFH * 4; // 33.6 MB
  float* hout  = (float*)(base + off);    off += (size_t)GB * GN * GC * 4;       // 0.5 MB
  float* f1    = (float*)(base + off);    off += (size_t)GB * GH * GN * 4;       // 0.5 MB
  float* f2    = (float*)(base + off);    off += (size_t)GB * GH * GN * 4;       // 0.5 MB
  float* f1b   = (float*)(base + off);    off += (size_t)GB * GN * 4;
  float* f2b   = (float*)(base + off);    off += (size_t)GB * GN * 4;            // ~53 MB

  if (ws_size < off) return;

  hipLaunchKernelGGL(k_pack_gemm1, dim3(1024 + 4096), dim3(256), 0, stream,
                     adj, mw, x, Whd, a1h, a2h, VT, f1, f2);
  hipLaunchKernelGGL(k_attn1, dim3(GB * GH * 4), dim3(256), 0, stream,
                     VT, mw, f1, f2, xcat);
  hipLaunchKernelGGL(k_gemm2, dim3(GB * 8), dim3(256), 0, stream,
                     xcat, Wo, a1o, a2o, hout, f1b, f2b);
  hipLaunchKernelGGL(k_attn2, dim3(GB * 64), dim3(256), 0, stream,
                     hout, mw, f1b, f2b, (float*)d_out);
}

// Round 5
// 158.252 us; speedup vs baseline: 1.4961x; 1.3516x over previous
//
#include <hip/hip_runtime.h>
#include <hip/hip_bf16.h>

// GAT batch: B=32, N=512, Fin=128, Fhid=64, H=8, C=16.  fp32 I/O.
#define GB 32
#define GN 512
#define GFIN 128
#define GFH 64
#define GH 8
#define GC 16

typedef short short8 __attribute__((ext_vector_type(8)));   // 8 bf16 (MFMA A/B frag)
typedef float f32x4 __attribute__((ext_vector_type(4)));    // MFMA C/D frag

__device__ __forceinline__ ushort f2bf(float f) {
  unsigned u = __float_as_uint(f);
  return (ushort)((u + 0x7FFFu + ((u >> 16) & 1u)) >> 16);  // RNE
}
__device__ __forceinline__ unsigned pk2(float a, float b) {
  float2 f2; f2.x = a; f2.y = b;
  __hip_bfloat162 h = __float22bfloat162_rn(f2);
  union { __hip_bfloat162 h; unsigned u; } cv;
  cv.h = h;
  return cv.u;
}
__device__ __forceinline__ short8 ones8() {
  short8 o;
#pragma unroll
  for (int i = 0; i < 8; ++i) o[i] = (short)0x3F80;  // bf16 1.0
  return o;
}

// ---------------------------------------------------------------------------
// K01: fused kernel. Blocks [0,1024): gemm1 (V^T + f1/f2). Blocks
// [1024,5120): adj bit-pack (ILP-8). Block 5120: W_out -> WoT bf16.
// ---------------------------------------------------------------------------
__global__ __launch_bounds__(256) void k_pack_gemm1(
    const int* __restrict__ adj, unsigned* __restrict__ mw,
    const float* __restrict__ xg, const float* __restrict__ Wg,
    const float* __restrict__ a1g, const float* __restrict__ a2g,
    ushort* __restrict__ VTg, float* __restrict__ f1g, float* __restrict__ f2g,
    const float* __restrict__ Wog, ushort* __restrict__ WoT) {
  __shared__ ushort Wt[64][136];    // W transposed [j][f] bf16
  __shared__ ushort xl[128][136];   // x row tile [row][f] bf16
  int blk = blockIdx.x;
  int tid = threadIdx.x;

  if (blk == 5120) {                // ---- W_out transpose+cvt: [512][16]->[16][512]
    for (int i = tid; i < 512 * GC; i += 256) {
      int k = i & 511, cc = i >> 9;
      WoT[cc * 512 + k] = f2bf(Wog[(size_t)k * GC + cc]);
    }
    return;
  }
  if (blk >= 1024) {                // ---- pack path, ILP-8 ----
    int pblk = blk - 1024;          // 4096 blocks x 2048 elements
    int lane = tid & 63;
    int base = pblk * 2048 + tid;
    int v[8];
#pragma unroll
    for (int it = 0; it < 8; ++it) v[it] = adj[(size_t)base + it * 256];
#pragma unroll
    for (int it = 0; it < 8; ++it) {
      unsigned long long m = __ballot(v[it] > 0);
      int idx = base + it * 256;
      if (lane == 0)       mw[idx >> 5] = (unsigned)m;
      else if (lane == 32) mw[idx >> 5] = (unsigned)(m >> 32);
    }
    return;
  }

  // ---- gemm1 path: blk = bh*4 + rq ----
  int bh = blk >> 2, rq = blk & 3;
  int b = bh >> 3, h = bh & 7;
  int r0 = rq * 128;
  int lane = tid & 63, w = tid >> 6;
  int c = lane & 15, q = lane >> 4;

  const float* Wh = Wg + (size_t)h * GFIN * GFH;
  for (int i = tid; i < GFIN * GFH; i += 256) {
    int f = i >> 6, j = i & 63;
    Wt[j][f] = f2bf(Wh[i]);
  }
  const float* xb = xg + ((size_t)b * GN + r0) * GFIN;
  for (int u = tid; u < 128 * 32; u += 256) {
    int row = u >> 5, c4 = u & 31;
    float4 xf = *(const float4*)&xb[(size_t)row * GFIN + c4 * 4];
    uint2 us;
    us.x = pk2(xf.x, xf.y);
    us.y = pk2(xf.z, xf.w);
    *(uint2*)&xl[row][c4 * 4] = us;
  }
  __syncthreads();

  short8 Bf[4][4];
#pragma unroll
  for (int cb = 0; cb < 4; ++cb)
#pragma unroll
    for (int kk = 0; kk < 4; ++kk)
      Bf[cb][kk] = *(const short8*)&Wt[cb * 16 + c][kk * 32 + q * 8];

  float a1v[4], a2v[4];
#pragma unroll
  for (int cb = 0; cb < 4; ++cb) {
    a1v[cb] = a1g[h * 64 + cb * 16 + c];
    a2v[cb] = a2g[h * 64 + cb * 16 + c];
  }

  f32x4 acc[2][4];
#pragma unroll
  for (int r = 0; r < 2; ++r)
#pragma unroll
    for (int cb = 0; cb < 4; ++cb) acc[r][cb] = (f32x4){0.f, 0.f, 0.f, 0.f};

#pragma unroll
  for (int kk = 0; kk < 4; ++kk) {
    short8 A0 = *(const short8*)&xl[(w * 2 + 0) * 16 + c][kk * 32 + q * 8];
    short8 A1 = *(const short8*)&xl[(w * 2 + 1) * 16 + c][kk * 32 + q * 8];
#pragma unroll
    for (int cb = 0; cb < 4; ++cb) {
      acc[0][cb] = __builtin_amdgcn_mfma_f32_16x16x32_bf16(A0, Bf[cb][kk], acc[0][cb], 0, 0, 0);
      acc[1][cb] = __builtin_amdgcn_mfma_f32_16x16x32_bf16(A1, Bf[cb][kk], acc[1][cb], 0, 0, 0);
    }
  }

  ushort* VT = VTg + (size_t)bh * GN * GFH;
  float* f1o = f1g + (size_t)bh * GN;
  float* f2o = f2g + (size_t)bh * GN;
#pragma unroll
  for (int rbi = 0; rbi < 2; ++rbi) {
    int rowb = r0 + (w * 2 + rbi) * 16 + q * 4;
    float v1[4] = {0.f, 0.f, 0.f, 0.f}, v2[4] = {0.f, 0.f, 0.f, 0.f};
#pragma unroll
    for (int cb = 0; cb < 4; ++cb) {
      f32x4 a = acc[rbi][cb];
      uint2 vs;
      vs.x = pk2(a[0], a[1]);
      vs.y = pk2(a[2], a[3]);
      *(uint2*)&VT[(size_t)(cb * 16 + c) * GN + rowb] = vs;
#pragma unroll
      for (int i = 0; i < 4; ++i) {
        v1[i] += a[i] * a1v[cb];
        v2[i] += a[i] * a2v[cb];
      }
    }
#pragma unroll
    for (int i = 0; i < 4; ++i) {
#pragma unroll
      for (int off = 1; off < 16; off <<= 1) {
        v1[i] += __shfl_xor(v1[i], off);
        v2[i] += __shfl_xor(v2[i], off);
      }
      if (c == 0) { f1o[rowb + i] = v1[i]; f2o[rowb + i] = v2[i]; }
    }
  }
}

// ---------------------------------------------------------------------------
// K2: layer-1 attention v3. grid 1024 = rq*256 + bh (XCD-friendly: 4 rq of one
// bh land on one XCD). Exp-factorized scores: p = max(E1*E2, e1*e2) masked.
// L via ones-MFMA (same C-layout rows as PV acc). xcat written bf16.
// ---------------------------------------------------------------------------
__global__ __launch_bounds__(256, 4) void k_attn1(
    const ushort* __restrict__ VTg, const unsigned* __restrict__ mwg,
    const float* __restrict__ f1g, const float* __restrict__ f2g,
    ushort* __restrict__ xcb) {
  __shared__ ushort P[32][520];
  int blk = blockIdx.x;
  int bh = blk & 255, rq = blk >> 8;
  int b = bh >> 3, h = bh & 7;
  int r0 = rq * 128;
  int tid = threadIdx.x, lane = tid & 63, w = tid >> 6;
  int c = lane & 15, q = lane >> 4;

  const unsigned* mwb = mwg + (size_t)b * GN * 16;
  const float* f1w = f1g + (size_t)bh * GN;
  const float* f2w = f2g + (size_t)bh * GN;

  // Column factors: E2 = exp(f2), e2 = exp(0.2 f2) for this lane's 8 cols.
  float4 fa = *(const float4*)&f2w[lane * 8];
  float4 fb = *(const float4*)&f2w[lane * 8 + 4];
  float E2[8], e2[8];
  {
    float f2v[8] = {fa.x, fa.y, fa.z, fa.w, fb.x, fb.y, fb.z, fb.w};
#pragma unroll
    for (int i = 0; i < 8; ++i) {
      E2[i] = __expf(f2v[i]);
      e2[i] = __expf(0.2f * f2v[i]);
    }
  }
  // Row factors for this wave's 32 rows, one per lane<32; shfl-broadcast later.
  float f1v = 0.f;
  if (lane < 32) f1v = f1w[r0 + ((lane >> 3) << 5) + w + ((lane & 7) << 2)];
  float E1v = __expf(f1v), e1v = __expf(0.2f * f1v);

  // B-frags from V^T (coalesced).
  const ushort* VT = VTg + (size_t)bh * GN * GFH + (size_t)(w * 16 + c) * GN + q * 8;
  short8 Bf[16];
#pragma unroll
  for (int kk = 0; kk < 16; ++kk) Bf[kk] = *(const short8*)&VT[kk * 32];
  const short8 ONES = ones8();

  for (int t = 0; t < 4; ++t) {
    int tb = r0 + t * 32;
    unsigned mword[8];
#pragma unroll
    for (int ri = 0; ri < 8; ++ri)
      mword[ri] = mwb[(size_t)(tb + w + 4 * ri) * 16 + (lane >> 2)];
#pragma unroll
    for (int ri = 0; ri < 8; ++ri) {
      float E1r = __shfl(E1v, t * 8 + ri);
      float e1r = __shfl(e1v, t * 8 + ri);
      unsigned mb = (mword[ri] >> (8 * (lane & 3))) & 0xffu;
      float p[8];
#pragma unroll
      for (int i = 0; i < 8; ++i) {
        float v = fmaxf(E1r * E2[i], e1r * e2[i]);  // exp(LeakyReLU(s))
        p[i] = ((mb >> i) & 1u) ? v : 0.f;
      }
      uint4 u;
      u.x = pk2(p[0], p[1]);
      u.y = pk2(p[2], p[3]);
      u.z = pk2(p[4], p[5]);
      u.w = pk2(p[6], p[7]);
      *(uint4*)&P[w + 4 * ri][lane * 8] = u;
    }
    __syncthreads();

    f32x4 acc0 = (f32x4){0.f, 0.f, 0.f, 0.f};
    f32x4 acc1 = (f32x4){0.f, 0.f, 0.f, 0.f};
    f32x4 aL0 = (f32x4){0.f, 0.f, 0.f, 0.f};
    f32x4 aL1 = (f32x4){0.f, 0.f, 0.f, 0.f};
#pragma unroll
    for (int kk = 0; kk < 16; ++kk) {
      short8 A0 = *(const short8*)&P[c][kk * 32 + q * 8];
      short8 A1 = *(const short8*)&P[16 + c][kk * 32 + q * 8];
      acc0 = __builtin_amdgcn_mfma_f32_16x16x32_bf16(A0, Bf[kk], acc0, 0, 0, 0);
      aL0  = __builtin_amdgcn_mfma_f32_16x16x32_bf16(A0, ONES,   aL0, 0, 0, 0);
      acc1 = __builtin_amdgcn_mfma_f32_16x16x32_bf16(A1, Bf[kk], acc1, 0, 0, 0);
      aL1  = __builtin_amdgcn_mfma_f32_16x16x32_bf16(A1, ONES,   aL1, 0, 0, 0);
    }
#pragma unroll
    for (int rbi = 0; rbi < 2; ++rbi) {
      f32x4 a = rbi ? acc1 : acc0;
      f32x4 aL = rbi ? aL1 : aL0;
#pragma unroll
      for (int i = 0; i < 4; ++i) {
        int row = tb + rbi * 16 + q * 4 + i;
        float v = a[i] / fmaxf(aL[i], 1e-30f);
        v = v > 0.f ? v : __expf(v) - 1.f;          // elu
        xcb[((size_t)(b * GN + row)) * 512 + h * 64 + w * 16 + c] = f2bf(v);
      }
    }
    __syncthreads();
  }
}

// ---------------------------------------------------------------------------
// K3: h_out = x_cat @ W_out via MFMA (bf16). Writes hT bf16 [b][c][row] +
// exact fp32 f1b/f2b. grid = B*8 (64 rows/block), 4 waves (16 rows each).
// ---------------------------------------------------------------------------
__global__ __launch_bounds__(256) void k_gemm2(
    const ushort* __restrict__ xcb, const ushort* __restrict__ WoT,
    const float* __restrict__ a1g, const float* __restrict__ a2g,
    ushort* __restrict__ hTg, float* __restrict__ f1b, float* __restrict__ f2b) {
  __shared__ ushort xl[64][520];
  int b = blockIdx.x >> 3, r0 = (blockIdx.x & 7) * 64;
  int tid = threadIdx.x, lane = tid & 63, w = tid >> 6;
  int c = lane & 15, q = lane >> 4;

  const ushort* xb = xcb + ((size_t)b * GN + r0) * 512;
  for (int i = tid; i < 64 * 64; i += 256) {    // 64 uint4 per row
    int row = i >> 6, c8 = i & 63;
    *(uint4*)&xl[row][c8 * 8] = *(const uint4*)&xb[(size_t)row * 512 + c8 * 8];
  }
  short8 Bf[16];
#pragma unroll
  for (int kk = 0; kk < 16; ++kk)
    Bf[kk] = *(const short8*)&WoT[(size_t)c * 512 + kk * 32 + q * 8];
  __syncthreads();

  f32x4 acc = (f32x4){0.f, 0.f, 0.f, 0.f};
#pragma unroll
  for (int kk = 0; kk < 16; ++kk) {
    short8 A = *(const short8*)&xl[w * 16 + c][kk * 32 + q * 8];
    acc = __builtin_amdgcn_mfma_f32_16x16x32_bf16(A, Bf[kk], acc, 0, 0, 0);
  }

  float a1v = a1g[c], a2v = a2g[c];
  int rowb = r0 + w * 16 + q * 4;
  uint2 vs;
  vs.x = pk2(acc[0], acc[1]);
  vs.y = pk2(acc[2], acc[3]);
  *(uint2*)&hTg[((size_t)b * GC + c) * 512 + rowb] = vs;
#pragma unroll
  for (int i = 0; i < 4; ++i) {
    float v1 = acc[i] * a1v, v2 = acc[i] * a2v;
#pragma unroll
    for (int off = 1; off < 16; off <<= 1) {
      v1 += __shfl_xor(v1, off);
      v2 += __shfl_xor(v2, off);
    }
    if (c == 0) {
      f1b[(size_t)b * GN + rowb + i] = v1;
      f2b[(size_t)b * GN + rowb + i] = v2;
    }
  }
}

// ---------------------------------------------------------------------------
// K4: layer-2 attention via MFMA (concat=False, fp32 out). grid = B*8
// (64 rows/block), 4 waves x 16 rows. Same exp-factorized scores; P bf16;
// L via ones-MFMA.
// ---------------------------------------------------------------------------
__global__ __launch_bounds__(256) void k_attn2(
    const ushort* __restrict__ hTg, const unsigned* __restrict__ mwg,
    const float* __restrict__ f1g, const float* __restrict__ f2g,
    float* __restrict__ outg) {
  __shared__ ushort P[64][520];
  int b = blockIdx.x >> 3, r0 = (blockIdx.x & 7) * 64;
  int tid = threadIdx.x, lane = tid & 63, w = tid >> 6;
  int c = lane & 15, q = lane >> 4;

  const unsigned* mwb = mwg + (size_t)b * GN * 16;
  const float* f1w = f1g + (size_t)b * GN;
  const float* f2w = f2g + (size_t)b * GN;

  float4 fa = *(const float4*)&f2w[lane * 8];
  float4 fb = *(const float4*)&f2w[lane * 8 + 4];
  float E2[8], e2[8];
  {
    float f2v[8] = {fa.x, fa.y, fa.z, fa.w, fb.x, fb.y, fb.z, fb.w};
#pragma unroll
    for (int i = 0; i < 8; ++i) {
      E2[i] = __expf(f2v[i]);
      e2[i] = __expf(0.2f * f2v[i]);
    }
  }
  float f1v = 0.f;
  if (lane < 16) f1v = f1w[r0 + w * 16 + lane];
  float E1v = __expf(f1v), e1v = __expf(0.2f * f1v);

  short8 Bf[16];
#pragma unroll
  for (int kk = 0; kk < 16; ++kk)
    Bf[kk] = *(const short8*)&hTg[((size_t)b * GC + c) * 512 + kk * 32 + q * 8];
  const short8 ONES = ones8();

  unsigned mword[16];
#pragma unroll
  for (int ri = 0; ri < 16; ++ri)
    mword[ri] = mwb[(size_t)(r0 + w * 16 + ri) * 16 + (lane >> 2)];

#pragma unroll
  for (int ri = 0; ri < 16; ++ri) {
    float E1r = __shfl(E1v, ri);
    float e1r = __shfl(e1v, ri);
    unsigned mb = (mword[ri] >> (8 * (lane & 3))) & 0xffu;
    float p[8];
#pragma unroll
    for (int i = 0; i < 8; ++i) {
      float v = fmaxf(E1r * E2[i], e1r * e2[i]);
      p[i] = ((mb >> i) & 1u) ? v : 0.f;
    }
    uint4 u;
    u.x = pk2(p[0], p[1]);
    u.y = pk2(p[2], p[3]);
    u.z = pk2(p[4], p[5]);
    u.w = pk2(p[6], p[7]);
    *(uint4*)&P[w * 16 + ri][lane * 8] = u;
  }
  __syncthreads();

  f32x4 acc = (f32x4){0.f, 0.f, 0.f, 0.f};
  f32x4 aL = (f32x4){0.f, 0.f, 0.f, 0.f};
#pragma unroll
  for (int kk = 0; kk < 16; ++kk) {
    short8 A = *(const short8*)&P[w * 16 + c][kk * 32 + q * 8];
    acc = __builtin_amdgcn_mfma_f32_16x16x32_bf16(A, Bf[kk], acc, 0, 0, 0);
    aL  = __builtin_amdgcn_mfma_f32_16x16x32_bf16(A, ONES, aL, 0, 0, 0);
  }
#pragma unroll
  for (int i = 0; i < 4; ++i) {
    int row = r0 + w * 16 + q * 4 + i;
    outg[((size_t)(b * GN + row)) * GC + c] = acc[i] / fmaxf(aL[i], 1e-30f);
  }
}

// ---------------------------------------------------------------------------
extern "C" void kernel_launch(void* const* d_in, const int* in_sizes, int n_in,
                              void* d_out, int out_size, void* d_ws, size_t ws_size,
                              hipStream_t stream) {
  (void)in_sizes; (void)n_in; (void)out_size;
  const float* x   = (const float*)d_in[0];
  const int*   adj = (const int*)d_in[1];
  const float* Whd = (const float*)d_in[2];
  const float* a1h = (const float*)d_in[3];
  const float* a2h = (const float*)d_in[4];
  const float* Wo  = (const float*)d_in[5];
  const float* a1o = (const float*)d_in[6];
  const float* a2o = (const float*)d_in[7];

  size_t off = 0;
  char* base = (char*)d_ws;
  unsigned* mw = (unsigned*)(base + off); off += (size_t)GB * GN * 16 * 4;       // 1 MB
  ushort* VT   = (ushort*)(base + off);   off += (size_t)GB * GH * GN * GFH * 2; // 16.8 MB
  ushort* xcb  = (ushort*)(base + off);   off += (size_t)GB * GN * 512 * 2;      // 16.8 MB
  ushort* WoT  = (ushort*)(base + off);   off += (size_t)GC * 512 * 2;           // 16 KB
  ushort* hT   = (ushort*)(base + off);   off += (size_t)GB * GC * GN * 2;       // 0.5 MB
  float* f1    = (float*)(base + off);    off += (size_t)GB * GH * GN * 4;       // 0.5 MB
  float* f2    = (float*)(base + off);    off += (size_t)GB * GH * GN * 4;       // 0.5 MB
  float* f1b   = (float*)(base + off);    off += (size_t)GB * GN * 4;
  float* f2b   = (float*)(base + off);    off += (size_t)GB * GN * 4;            // ~36.4 MB

  if (ws_size < off) return;

  hipLaunchKernelGGL(k_pack_gemm1, dim3(5121), dim3(256), 0, stream,
                     adj, mw, x, Whd, a1h, a2h, VT, f1, f2, Wo, WoT);
  hipLaunchKernelGGL(k_attn1, dim3(1024), dim3(256), 0, stream,
                     VT, mw, f1, f2, xcb);
  hipLaunchKernelGGL(k_gemm2, dim3(GB * 8), dim3(256), 0, stream,
                     xcb, WoT, a1o, a2o, hT, f1b, f2b);
  hipLaunchKernelGGL(k_attn2, dim3(GB * 8), dim3(256), 0, stream,
                     hT, mw, f1b, f2b, (float*)d_out);
}